// Round 1
// baseline (148.061 us; speedup 1.0000x reference)
//
#include <hip/hip_runtime.h>

#define KK 8
#define CC 16

// Transpose features (C,P) -> (P,C) so each point's feature vector is one
// contiguous 64B segment (single L2 line pair instead of 16 scattered lines).
__global__ void transpose_feat(const float* __restrict__ f,
                               float* __restrict__ ft, int P) {
    int p = blockIdx.x * blockDim.x + threadIdx.x;
    if (p >= P) return;
    float tmp[CC];
#pragma unroll
    for (int c = 0; c < CC; ++c) tmp[c] = f[(size_t)c * P + p];
    float4* dst = (float4*)(ft + (size_t)p * CC);
    dst[0] = make_float4(tmp[0], tmp[1], tmp[2], tmp[3]);
    dst[1] = make_float4(tmp[4], tmp[5], tmp[6], tmp[7]);
    dst[2] = make_float4(tmp[8], tmp[9], tmp[10], tmp[11]);
    dst[3] = make_float4(tmp[12], tmp[13], tmp[14], tmp[15]);
}

// One thread per pixel. TRANS=true: feat is (P,C) transposed in ws.
// TRANS=false: feat is original (C,P) with stride P (fallback if ws too small).
template <bool TRANS>
__global__ void render_kernel(const int* __restrict__ idx,
                              const float* __restrict__ dists,
                              const float* __restrict__ radii,
                              const float* __restrict__ feat,
                              float* __restrict__ out, int npix, int P) {
    int pix = blockIdx.x * blockDim.x + threadIdx.x;
    if (pix >= npix) return;

    const int4* ip = (const int4*)(idx + (size_t)pix * KK);
    const float4* dp = (const float4*)(dists + (size_t)pix * KK);
    int4 i0 = ip[0], i1 = ip[1];
    float4 dv0 = dp[0], dv1 = dp[1];
    int ids[KK] = {i0.x, i0.y, i0.z, i0.w, i1.x, i1.y, i1.z, i1.w};
    float ds[KK] = {dv0.x, dv0.y, dv0.z, dv0.w, dv1.x, dv1.y, dv1.z, dv1.w};

    float4 acc0 = make_float4(0.f, 0.f, 0.f, 0.f);
    float4 acc1 = make_float4(0.f, 0.f, 0.f, 0.f);
    float4 acc2 = make_float4(0.f, 0.f, 0.f, 0.f);
    float4 acc3 = make_float4(0.f, 0.f, 0.f, 0.f);
    float T = 1.0f;

#pragma unroll
    for (int k = 0; k < KK; ++k) {
        int id = ids[k];
        if (id >= 0) {
            float r = radii[id];
            float w = 1.0f - ds[k] / (r * r);
            float a = w * T;
            T *= (1.0f - w);
            float4 f0, f1, f2, f3;
            if (TRANS) {
                const float4* fp = (const float4*)(feat + (size_t)id * CC);
                f0 = fp[0];
                f1 = fp[1];
                f2 = fp[2];
                f3 = fp[3];
            } else {
                const float* fb = feat + id;
                f0 = make_float4(fb[0 * (size_t)P], fb[1 * (size_t)P],
                                 fb[2 * (size_t)P], fb[3 * (size_t)P]);
                f1 = make_float4(fb[4 * (size_t)P], fb[5 * (size_t)P],
                                 fb[6 * (size_t)P], fb[7 * (size_t)P]);
                f2 = make_float4(fb[8 * (size_t)P], fb[9 * (size_t)P],
                                 fb[10 * (size_t)P], fb[11 * (size_t)P]);
                f3 = make_float4(fb[12 * (size_t)P], fb[13 * (size_t)P],
                                 fb[14 * (size_t)P], fb[15 * (size_t)P]);
            }
            acc0.x += a * f0.x; acc0.y += a * f0.y; acc0.z += a * f0.z; acc0.w += a * f0.w;
            acc1.x += a * f1.x; acc1.y += a * f1.y; acc1.z += a * f1.z; acc1.w += a * f1.w;
            acc2.x += a * f2.x; acc2.y += a * f2.y; acc2.z += a * f2.z; acc2.w += a * f2.w;
            acc3.x += a * f3.x; acc3.y += a * f3.y; acc3.z += a * f3.z; acc3.w += a * f3.w;
        }
    }

    float4* op = (float4*)(out + (size_t)pix * CC);
    op[0] = acc0;
    op[1] = acc1;
    op[2] = acc2;
    op[3] = acc3;
}

extern "C" void kernel_launch(void* const* d_in, const int* in_sizes, int n_in,
                              void* d_out, int out_size, void* d_ws, size_t ws_size,
                              hipStream_t stream) {
    const int* idx = (const int*)d_in[0];
    const float* dists = (const float*)d_in[1];
    const float* radii = (const float*)d_in[2];
    const float* features = (const float*)d_in[3];
    float* out = (float*)d_out;

    int P = in_sizes[2];            // 200000
    int npix = in_sizes[0] / KK;    // B*H*W = 1048576

    size_t need = (size_t)P * CC * sizeof(float);  // 12.8 MB
    if (ws_size >= need) {
        float* featT = (float*)d_ws;
        transpose_feat<<<(P + 255) / 256, 256, 0, stream>>>(features, featT, P);
        render_kernel<true><<<(npix + 255) / 256, 256, 0, stream>>>(
            idx, dists, radii, featT, out, npix, P);
    } else {
        render_kernel<false><<<(npix + 255) / 256, 256, 0, stream>>>(
            idx, dists, radii, features, out, npix, P);
    }
}

// Round 2
// 112.057 us; speedup vs baseline: 1.3213x; 1.3213x over previous
//
#include <hip/hip_runtime.h>

#define KK 8
#define CC 16

static __device__ __forceinline__ unsigned short f32_to_bf16(float x) {
    unsigned int b = __float_as_uint(x);
    unsigned int r = b + 0x7FFFu + ((b >> 16) & 1u);
    return (unsigned short)(r >> 16);
}
static __device__ __forceinline__ float bf16_to_f32(unsigned short u) {
    return __uint_as_float(((unsigned int)u) << 16);
}

// Prep: features (C,P) f32 -> (P,C) bf16 packed records (32B/point), and
// inv_r2[p] = 1/r^2 (f32). Both live in d_ws.
__global__ void prep_kernel(const float* __restrict__ f,
                            const float* __restrict__ radii,
                            unsigned short* __restrict__ ft,
                            float* __restrict__ inv_r2, int P) {
    int p = blockIdx.x * blockDim.x + threadIdx.x;
    if (p >= P) return;
    float r = radii[p];
    inv_r2[p] = 1.0f / (r * r);
    unsigned int w[8];
#pragma unroll
    for (int j = 0; j < 8; ++j) {
        unsigned int lo = f32_to_bf16(f[(size_t)(2 * j) * P + p]);
        unsigned int hi = f32_to_bf16(f[(size_t)(2 * j + 1) * P + p]);
        w[j] = lo | (hi << 16);
    }
    uint4* dst = (uint4*)(ft + (size_t)p * CC);
    dst[0] = make_uint4(w[0], w[1], w[2], w[3]);
    dst[1] = make_uint4(w[4], w[5], w[6], w[7]);
}

// 4 lanes per pixel; lane q owns channels [4q, 4q+4). The 4 lanes' feature
// loads for one fragment are consecutive 8B chunks of one 32B record ->
// merged into a single coalesced request. idx/dists loads are same-address
// within the quad (broadcast). Output store is fully coalesced.
__global__ void render_kernel(const int* __restrict__ idx,
                              const float* __restrict__ dists,
                              const float* __restrict__ inv_r2,
                              const unsigned short* __restrict__ ft,
                              float* __restrict__ out, int npix) {
    int tid = blockIdx.x * blockDim.x + threadIdx.x;
    int pix = tid >> 2;
    int q = tid & 3;
    if (pix >= npix) return;

    const int4* ip = (const int4*)(idx + (size_t)pix * KK);
    const float4* dp = (const float4*)(dists + (size_t)pix * KK);
    int4 i0 = ip[0], i1 = ip[1];
    float4 dv0 = dp[0], dv1 = dp[1];
    int ids[KK] = {i0.x, i0.y, i0.z, i0.w, i1.x, i1.y, i1.z, i1.w};
    float ds[KK] = {dv0.x, dv0.y, dv0.z, dv0.w, dv1.x, dv1.y, dv1.z, dv1.w};

    float a0 = 0.f, a1 = 0.f, a2 = 0.f, a3 = 0.f;
    float T = 1.0f;

#pragma unroll
    for (int k = 0; k < KK; ++k) {
        int id = ids[k];
        if (id >= 0) {
            float ir2 = inv_r2[id];                 // broadcast within quad
            float w = 1.0f - ds[k] * ir2;
            float a = w * T;
            T *= (1.0f - w);
            // 8B of the point's 32B bf16 record, consecutive across the quad
            uint2 pk = *(const uint2*)(ft + (size_t)id * CC + q * 4);
            a0 += a * bf16_to_f32((unsigned short)(pk.x & 0xFFFF));
            a1 += a * bf16_to_f32((unsigned short)(pk.x >> 16));
            a2 += a * bf16_to_f32((unsigned short)(pk.y & 0xFFFF));
            a3 += a * bf16_to_f32((unsigned short)(pk.y >> 16));
        }
    }

    float4* op = (float4*)(out + (size_t)pix * CC + q * 4);
    op[0] = make_float4(a0, a1, a2, a3);
}

extern "C" void kernel_launch(void* const* d_in, const int* in_sizes, int n_in,
                              void* d_out, int out_size, void* d_ws, size_t ws_size,
                              hipStream_t stream) {
    const int* idx = (const int*)d_in[0];
    const float* dists = (const float*)d_in[1];
    const float* radii = (const float*)d_in[2];
    const float* features = (const float*)d_in[3];
    float* out = (float*)d_out;

    int P = in_sizes[2];          // 200000
    int npix = in_sizes[0] / KK;  // B*H*W = 1048576

    unsigned short* ft = (unsigned short*)d_ws;                 // P*32B = 6.4MB
    float* inv_r2 = (float*)((char*)d_ws + (size_t)P * CC * 2); // +800KB

    prep_kernel<<<(P + 255) / 256, 256, 0, stream>>>(features, radii, ft, inv_r2, P);

    int nthreads = npix * 4;
    render_kernel<<<(nthreads + 255) / 256, 256, 0, stream>>>(
        idx, dists, inv_r2, ft, out, npix);
}